// Round 1
// 4850.192 us; speedup vs baseline: 3.5860x; 3.5860x over previous
//
#include <hip/hip_runtime.h>

typedef unsigned short u16;
typedef __attribute__((ext_vector_type(8))) short short8;
typedef __attribute__((ext_vector_type(4))) float floatx4;

__device__ __forceinline__ u16 f2bf(float f) {
  union { float f; unsigned int u; } v; v.f = f;
  unsigned int r = v.u + 0x7FFFu + ((v.u >> 16) & 1u);
  return (u16)(r >> 16);
}
__device__ __forceinline__ float b2f(u16 h) {
  union { unsigned int u; float f; } v; v.u = ((unsigned int)h) << 16;
  return v.f;
}
__device__ __forceinline__ float sigmoidf_(float x) {
  return 1.0f / (1.0f + __expf(-x));
}
__device__ __forceinline__ float tanhf_(float x) {
  float xx = fminf(fmaxf(x, -15.0f), 15.0f);
  float e = __expf(2.0f * xx);
  return (e - 1.0f) / (e + 1.0f);
}

// ---- MALL-direct (agent-coherent, cache-bypassing) data movement ----
// sc1 loads/stores are what the compiler emits for agent-scope atomics on
// gfx950: they read/write the coherence point (MALL) directly, so NO
// buffer_wbl2 / buffer_inv fences are needed for cross-WG visibility.
__device__ __forceinline__ void load4_sc(const short8* p, short8& a, short8& b,
                                         short8& c, short8& d) {
  asm volatile(
      "global_load_dwordx4 %0, %4, off sc1\n\t"
      "global_load_dwordx4 %1, %4, off offset:16 sc1\n\t"
      "global_load_dwordx4 %2, %4, off offset:32 sc1\n\t"
      "global_load_dwordx4 %3, %4, off offset:48 sc1\n\t"
      "s_waitcnt vmcnt(0)"
      : "=&v"(a), "=&v"(b), "=&v"(c), "=&v"(d)
      : "v"(p)
      : "memory");
}
__device__ __forceinline__ void load8_sc(const short8* p0, const short8* p1,
                                         short8& a0, short8& a1, short8& a2, short8& a3,
                                         short8& b0, short8& b1, short8& b2, short8& b3) {
  asm volatile(
      "global_load_dwordx4 %0, %8, off sc1\n\t"
      "global_load_dwordx4 %1, %8, off offset:16 sc1\n\t"
      "global_load_dwordx4 %2, %8, off offset:32 sc1\n\t"
      "global_load_dwordx4 %3, %8, off offset:48 sc1\n\t"
      "global_load_dwordx4 %4, %9, off sc1\n\t"
      "global_load_dwordx4 %5, %9, off offset:16 sc1\n\t"
      "global_load_dwordx4 %6, %9, off offset:32 sc1\n\t"
      "global_load_dwordx4 %7, %9, off offset:48 sc1\n\t"
      "s_waitcnt vmcnt(0)"
      : "=&v"(a0), "=&v"(a1), "=&v"(a2), "=&v"(a3),
        "=&v"(b0), "=&v"(b1), "=&v"(b2), "=&v"(b3)
      : "v"(p0), "v"(p1)
      : "memory");
}
__device__ __forceinline__ void store_u16_sc(u16* p, unsigned int v) {
  asm volatile("global_store_short %0, %1, off sc1" :: "v"(p), "v"(v) : "memory");
}
// Drain this wave's outstanding (asm) stores so the post-barrier flag store
// is ordered after all data stores reaching MALL. (Compiler's barrier lowering
// does not know about vmcnt events from inline asm.)
#define VM_DRAIN() asm volatile("s_waitcnt vmcnt(0)" ::: "memory")

// LDS swizzles (bank-conflict fixes):
//  - TILE staging writes were 16-way conflicted (kq-stride 1024B == 0 mod 32
//    banks); XOR the [16] row index with (kq&7).
//  - WA/WB reads collapse g (g*1024B == 0 mod banks); spread with q/g XOR.
#define FW(kq, g) (((((kq) >> 2) << 1) ^ (g)) & 7)

// ---- fp32 -> bf16 bulk convert (x) ----
__global__ void convert_f32_bf16(const float* __restrict__ in, u16* __restrict__ out, int n8) {
  int idx = blockIdx.x * blockDim.x + threadIdx.x;
  if (idx >= n8) return;
  const float4* s = (const float4*)in + (size_t)idx * 2;
  float4 a = s[0], b = s[1];
  union { short8 v; u16 u[8]; } o;
  o.u[0] = f2bf(a.x); o.u[1] = f2bf(a.y); o.u[2] = f2bf(a.z); o.u[3] = f2bf(a.w);
  o.u[4] = f2bf(b.x); o.u[5] = f2bf(b.y); o.u[6] = f2bf(b.z); o.u[7] = f2bf(b.w);
  ((short8*)out)[idx] = o.v;
}

// ---- W [512][2048] fp32 -> Wt [2048][512] bf16 ----
__global__ void transpose_to_bf16(const float* __restrict__ W, u16* __restrict__ Wt) {
  __shared__ u16 tile[64][65];
  int kb = blockIdx.x * 64;
  int nb = blockIdx.y * 64;
  int tx = threadIdx.x & 63;
  int ty = threadIdx.x >> 6;
#pragma unroll
  for (int jj = 0; jj < 16; jj++) {
    int rr = ty + jj * 4;
    tile[tx][rr] = f2bf(W[(size_t)(kb + rr) * 2048 + nb + tx]);
  }
  __syncthreads();
#pragma unroll
  for (int jj = 0; jj < 16; jj++) {
    int rr = ty + jj * 4;
    Wt[(size_t)(nb + rr) * 512 + kb + tx] = tile[rr][tx];
  }
}

// ---- xz = A(bf16 [M][512]) @ Bt(bf16 [2048][512]) + bias, INTERLEAVED output ----
__global__ __launch_bounds__(256) void gemm_xz(
    const u16* __restrict__ A, const u16* __restrict__ Bt,
    const float* __restrict__ bias, u16* __restrict__ C) {
  __shared__ short8 lds_a[4][4][64];
  __shared__ short8 lds_b[4][4][128];
  int tid = threadIdx.x;
  int tb = blockIdx.x * 64;
  int hb = blockIdx.y * 32;
  int lane = tid & 63, w = tid >> 6;
  int l15 = lane & 15, g = lane >> 4;
  int am = tid >> 2, aq = tid & 3;
  int nc = tid >> 1, bh = tid & 1;
  int bgate = nc >> 5, bc = nc & 31;
  const short8* srcA = (const short8*)(A + (size_t)(tb + am) * 512) + aq * 4;
  const short8* srcB = (const short8*)(Bt + (size_t)(bgate * 512 + hb + bc) * 512) + bh * 8;
  float bv[8];
#pragma unroll
  for (int gate = 0; gate < 4; gate++) {
    bv[gate * 2 + 0] = bias[gate * 512 + hb + l15];
    bv[gate * 2 + 1] = bias[gate * 512 + hb + 16 + l15];
  }
  floatx4 acc[8];
#pragma unroll
  for (int i = 0; i < 8; i++) acc[i] = (floatx4){0.f, 0.f, 0.f, 0.f};

  for (int ko = 0; ko < 4; ko++) {
    __syncthreads();
#pragma unroll
    for (int i = 0; i < 4; i++) lds_a[aq][i][am] = srcA[ko * 16 + i];
#pragma unroll
    for (int i = 0; i < 8; i++) lds_b[bh * 2 + (i >> 2)][i & 3][nc] = srcB[ko * 16 + i];
    __syncthreads();
#pragma unroll
    for (int kb = 0; kb < 4; kb++) {
      short8 a = lds_a[kb][g][w * 16 + l15];
#pragma unroll
      for (int nt = 0; nt < 8; nt++) {
        short8 b = lds_b[kb][g][nt * 16 + l15];
        acc[nt] = __builtin_amdgcn_mfma_f32_16x16x32_bf16(a, b, acc[nt], 0, 0, 0);
      }
    }
  }
  ushort4* Cv = (ushort4*)C;
#pragma unroll
  for (int hp = 0; hp < 2; hp++) {
    int hcol = hb + hp * 16 + l15;
#pragma unroll
    for (int rr = 0; rr < 4; rr++) {
      int row = w * 16 + g * 4 + rr;
      ushort4 v;
      v.x = f2bf(acc[0 + hp][rr] + bv[0 * 2 + hp]);
      v.y = f2bf(acc[2 + hp][rr] + bv[1 * 2 + hp]);
      v.z = f2bf(acc[4 + hp][rr] + bv[2 * 2 + hp]);
      v.w = f2bf(acc[6 + hp][rr] + bv[3 * 2 + hp]);
      Cv[(size_t)(tb + row) * 512 + hcol] = v;
    }
  }
}

// ---- fused 2-layer pipelined persistent LSTM (fence-free MALL handoff) ----
__global__ __launch_bounds__(256) void lstm_fused(
    const u16* __restrict__ xz0, const u16* __restrict__ Wh0t,
    const u16* __restrict__ Wx1t, const u16* __restrict__ Wh1t,
    const float* __restrict__ b1,
    u16* __restrict__ hbuf0, u16* __restrict__ hbuf1,
    u16* __restrict__ y0,
    unsigned int* flags0, unsigned int* flags1,
    float* __restrict__ out, float* __restrict__ hfin, float* __restrict__ cfin) {
  __shared__ short8 WA[16][4][64];    // 64KB: Wh slice
  __shared__ short8 WB[16][4][64];    // 64KB: Wx1 slice (layer1 only)
  __shared__ short8 TILE[16][4][16];  // 16KB: h/y staging (swizzled)
  __shared__ float zbuf[16 * 68];     // 4.25KB: z scratch (no longer unioned w/ TILE)

  int tid = threadIdx.x;
  int wg = blockIdx.x;
  int layer = wg >> 7;
  int lwg = wg & 127;
  int rb = lwg >> 5, cg = lwg & 31;
  int lane = tid & 63, w = tid >> 6;
  int l15 = lane & 15, g = lane >> 4;
  int brow = rb * 16;
  int r = tid >> 4, j = tid & 15;
  int mm = tid >> 4, kq = tid & 15;

  {
    int n = tid >> 2, q = tid & 3;
    int gate = n >> 4, nloc = n & 15;
    const u16* WhT = layer ? Wh1t : Wh0t;
    const short8* src = (const short8*)(WhT + (size_t)(gate * 512 + cg * 16 + nloc) * 512) + q * 16;
#pragma unroll
    for (int i = 0; i < 16; i++)
      WA[q * 4 + (i >> 2)][i & 3][n ^ FW(q * 4 + (i >> 2), i & 3)] = src[i];
    if (layer) {
      const short8* sx = (const short8*)(Wx1t + (size_t)(gate * 512 + cg * 16 + nloc) * 512) + q * 16;
#pragma unroll
      for (int i = 0; i < 16; i++)
        WB[q * 4 + (i >> 2)][i & 3][n ^ FW(q * 4 + (i >> 2), i & 3)] = sx[i];
    }
  }

  u16* hb = layer ? hbuf1 : hbuf0;
  unsigned int* myflags = (layer ? flags1 : flags0) + rb * 32;
  unsigned int* l0flags = flags0 + rb * 32;
  float* z = zbuf;
  float c = 0.0f;
  float* hfinL = hfin + layer * 32768;
  float* cfinL = cfin + layer * 32768;
  int hcol = cg * 16 + j;

  if (layer == 0) {
    const ushort4* xzp = (const ushort4*)xz0 + (size_t)(brow + r) * 524288 + (size_t)hcol;
    ushort4 xzv = xzp[0];
    for (int t = 0; t < 1024; t++) {
      if (t > 0) {
        if (tid < 64) {
          while (1) {
            unsigned int v = (lane < 32)
                ? __hip_atomic_load(&myflags[lane], __ATOMIC_RELAXED, __HIP_MEMORY_SCOPE_AGENT)
                : 0xFFFFFFFFu;
            if (__all((int)(v >= (unsigned int)t))) break;
            __builtin_amdgcn_s_sleep(1);
          }
          // no acquire fence: data loads below bypass caches (sc1)
        }
        __syncthreads();
      }
      {
        const short8* hs = (const short8*)(hb + ((size_t)(t & 1)) * 32768 + (size_t)(brow + mm) * 512) + kq * 4;
        short8 h0, h1, h2, h3;
        load4_sc(hs, h0, h1, h2, h3);
        int ms = mm ^ (kq & 7);
        TILE[kq][0][ms] = h0; TILE[kq][1][ms] = h1; TILE[kq][2][ms] = h2; TILE[kq][3][ms] = h3;
      }
      __syncthreads();
      floatx4 acc = (floatx4){0.f, 0.f, 0.f, 0.f};
#pragma unroll
      for (int kb = 0; kb < 16; kb++)
        acc = __builtin_amdgcn_mfma_f32_16x16x32_bf16(
            TILE[kb][g][l15 ^ (kb & 7)], WA[kb][g][(w * 16 + l15) ^ FW(kb, g)], acc, 0, 0, 0);
      // zbuf is disjoint from TILE: no barrier needed before z writes
#pragma unroll
      for (int rr = 0; rr < 4; rr++) z[(g * 4 + rr) * 68 + w * 16 + l15] = acc[rr];
      __syncthreads();
      float zi = z[r * 68 + 0 + j] + b2f(xzv.x);
      float zf = z[r * 68 + 16 + j] + b2f(xzv.y);
      float zg = z[r * 68 + 32 + j] + b2f(xzv.z);
      float zo = z[r * 68 + 48 + j] + b2f(xzv.w);
      float ig = sigmoidf_(zi), fg = sigmoidf_(zf), og = sigmoidf_(zo);
      float gg = tanhf_(zg);
      c = fg * c + ig * gg;
      float hn = og * tanhf_(c);
      size_t tok = (size_t)(brow + r) * 1024 + t;
      unsigned int hnb = (unsigned int)f2bf(hn);
      store_u16_sc(&hb[((size_t)((t + 1) & 1)) * 32768 + (size_t)(brow + r) * 512 + hcol], hnb);
      store_u16_sc(&y0[tok * 512 + hcol], hnb);
      if (t == 1023) {
        hfinL[(size_t)(brow + r) * 512 + hcol] = hn;
        cfinL[(size_t)(brow + r) * 512 + hcol] = c;
      }
      VM_DRAIN();       // each wave drains its sc1 stores to MALL
      __syncthreads();  // all waves drained before flag publish
      if (tid == 0) {
        __hip_atomic_store(&myflags[cg], (unsigned int)(t + 1), __ATOMIC_RELAXED, __HIP_MEMORY_SCOPE_AGENT);
      }
      if (t < 1023) xzv = xzp[(size_t)(t + 1) * 512];  // prefetch; hidden by next poll
    }
  } else {
    float b1r[4];
#pragma unroll
    for (int gate = 0; gate < 4; gate++) b1r[gate] = b1[gate * 512 + hcol];
    for (int t = 0; t < 1024; t++) {
      if (tid < 64) {
        unsigned int tgt = (lane < 32) ? (unsigned int)(t + 1) : (unsigned int)t;
        unsigned int* fp = (lane < 32) ? &l0flags[lane] : &myflags[lane - 32];
        while (1) {
          unsigned int v = __hip_atomic_load(fp, __ATOMIC_RELAXED, __HIP_MEMORY_SCOPE_AGENT);
          if (__all((int)(v >= tgt))) break;
          __builtin_amdgcn_s_sleep(1);
        }
      }
      __syncthreads();
      const short8* ys = (const short8*)(y0 + ((size_t)(brow + mm) * 1024 + t) * 512) + kq * 4;
      const short8* hs = (const short8*)(hb + ((size_t)(t & 1)) * 32768 + (size_t)(brow + mm) * 512) + kq * 4;
      short8 ya, yb, yc, yd, h0, h1, h2, h3;
      load8_sc(ys, hs, ya, yb, yc, yd, h0, h1, h2, h3);
      int ms = mm ^ (kq & 7);
      TILE[kq][0][ms] = ya; TILE[kq][1][ms] = yb; TILE[kq][2][ms] = yc; TILE[kq][3][ms] = yd;
      __syncthreads();
      floatx4 acc = (floatx4){0.f, 0.f, 0.f, 0.f};
#pragma unroll
      for (int kb = 0; kb < 16; kb++)
        acc = __builtin_amdgcn_mfma_f32_16x16x32_bf16(
            TILE[kb][g][l15 ^ (kb & 7)], WB[kb][g][(w * 16 + l15) ^ FW(kb, g)], acc, 0, 0, 0);
      __syncthreads();
      TILE[kq][0][ms] = h0; TILE[kq][1][ms] = h1; TILE[kq][2][ms] = h2; TILE[kq][3][ms] = h3;
      __syncthreads();
#pragma unroll
      for (int kb = 0; kb < 16; kb++)
        acc = __builtin_amdgcn_mfma_f32_16x16x32_bf16(
            TILE[kb][g][l15 ^ (kb & 7)], WA[kb][g][(w * 16 + l15) ^ FW(kb, g)], acc, 0, 0, 0);
#pragma unroll
      for (int rr = 0; rr < 4; rr++) z[(g * 4 + rr) * 68 + w * 16 + l15] = acc[rr];
      __syncthreads();
      float zi = z[r * 68 + 0 + j] + b1r[0];
      float zf = z[r * 68 + 16 + j] + b1r[1];
      float zg = z[r * 68 + 32 + j] + b1r[2];
      float zo = z[r * 68 + 48 + j] + b1r[3];
      float ig = sigmoidf_(zi), fg = sigmoidf_(zf), og = sigmoidf_(zo);
      float gg = tanhf_(zg);
      c = fg * c + ig * gg;
      float hn = og * tanhf_(c);
      size_t tok = (size_t)(brow + r) * 1024 + t;
      store_u16_sc(&hb[((size_t)((t + 1) & 1)) * 32768 + (size_t)(brow + r) * 512 + hcol],
                   (unsigned int)f2bf(hn));
      out[tok * 512 + hcol] = hn;
      if (t == 1023) {
        hfinL[(size_t)(brow + r) * 512 + hcol] = hn;
        cfinL[(size_t)(brow + r) * 512 + hcol] = c;
      }
      VM_DRAIN();
      __syncthreads();
      if (tid == 0 && t < 1023) {
        __hip_atomic_store(&myflags[cg], (unsigned int)(t + 1), __ATOMIC_RELAXED, __HIP_MEMORY_SCOPE_AGENT);
      }
    }
  }
}

extern "C" void kernel_launch(void* const* d_in, const int* in_sizes, int n_in,
                              void* d_out, int out_size, void* d_ws, size_t ws_size,
                              hipStream_t stream) {
  const float* x   = (const float*)d_in[0];
  const float* Wx0 = (const float*)d_in[1];
  const float* Wh0 = (const float*)d_in[2];
  const float* b0  = (const float*)d_in[3];
  const float* Wx1 = (const float*)d_in[4];
  const float* Wh1 = (const float*)d_in[5];
  const float* b1  = (const float*)d_in[6];
  float* out = (float*)d_out;
  char* ws = (char*)d_ws;

  const size_t OFF_XZ   = 0;                       // 65536*2048*2 = 268435456
  const size_t OFF_XY   = 268435456;               // x_bf then y0_bf (67108864)
  const size_t OFF_WX0T = 335544320;               // 2MB each
  const size_t OFF_WH0T = 337641472;
  const size_t OFF_WX1T = 339738624;
  const size_t OFF_WH1T = 341835776;
  const size_t OFF_HB0  = 343932928;               // 131072
  const size_t OFF_HB1  = 344064000;               // 131072
  const size_t OFF_FL0  = 344195072;               // 512
  const size_t OFF_FL1  = 344195584;               // 512
  const size_t NEED     = OFF_FL1 + 512;
  if (ws_size < NEED) return;

  u16* xz_bf = (u16*)(ws + OFF_XZ);
  u16* xy_bf = (u16*)(ws + OFF_XY);
  u16* Wx0t  = (u16*)(ws + OFF_WX0T);
  u16* Wh0t  = (u16*)(ws + OFF_WH0T);
  u16* Wx1t  = (u16*)(ws + OFF_WX1T);
  u16* Wh1t  = (u16*)(ws + OFF_WH1T);
  u16* hbuf0 = (u16*)(ws + OFF_HB0);
  u16* hbuf1 = (u16*)(ws + OFF_HB1);
  unsigned int* flags0 = (unsigned int*)(ws + OFF_FL0);
  unsigned int* flags1 = (unsigned int*)(ws + OFF_FL1);

  (void)hipMemsetAsync(ws + OFF_HB0, 0, 131072 * 2 + 1024, stream);

  convert_f32_bf16<<<16384, 256, 0, stream>>>(x, xy_bf, 4194304);
  transpose_to_bf16<<<dim3(8, 32), 256, 0, stream>>>(Wx0, Wx0t);
  transpose_to_bf16<<<dim3(8, 32), 256, 0, stream>>>(Wh0, Wh0t);
  transpose_to_bf16<<<dim3(8, 32), 256, 0, stream>>>(Wx1, Wx1t);
  transpose_to_bf16<<<dim3(8, 32), 256, 0, stream>>>(Wh1, Wh1t);

  gemm_xz<<<dim3(1024, 16), 256, 0, stream>>>(xy_bf, Wx0t, b0, xz_bf);

  float* hfin = out + 33554432;
  float* cfin = out + 33554432 + 65536;
  lstm_fused<<<256, 256, 0, stream>>>(xz_bf, Wh0t, Wx1t, Wh1t, b1,
                                      hbuf0, hbuf1, xy_bf, flags0, flags1,
                                      out, hfin, cfin);
}